// Round 3
// baseline (2279.586 us; speedup 1.0000x reference)
//
#include <hip/hip_runtime.h>
#include <stdint.h>

typedef __bf16 bf16x8_t __attribute__((ext_vector_type(8)));
typedef float  f32x4_t  __attribute__((ext_vector_type(4)));

#define MFMA_BF16(A, Bv, C) __builtin_amdgcn_mfma_f32_16x16x32_bf16((A), (Bv), (C), 0, 0, 0)

static constexpr int BB = 16;      // batch
static constexpr int LL = 1024;    // seq len
static constexpr int DD = 2048;    // input dim
static constexpr int HH = 512;     // hidden
static constexpr int GG = 4 * HH;  // 2048 gate rows
static constexpr int MM = BB * LL; // 16384

// ---- workspace layout (bytes) ----
static constexpr size_t XBF_OFF   = 0;                                    // x bf16 [MM][DD]
static constexpr size_t WIHBF_OFF = XBF_OFF   + (size_t)MM * DD * 2;      // W_ih bf16 [GG][DD]
static constexpr size_t WHHBF_OFF = WIHBF_OFF + (size_t)GG * DD * 2;      // W_hh bf16 [GG][HH]
static constexpr size_t XGBF_OFF  = WHHBF_OFF + (size_t)GG * HH * 2;      // xg bf16 [MM][GG]
static constexpr size_t GARR_OFF  = XGBF_OFF  + (size_t)MM * GG * 2;      // g f32 [MM]
static constexpr size_t PART_OFF  = GARR_OFF  + (size_t)MM * 4;           // partials f32 [BB][8][HH]
static constexpr size_t TBUF_OFF  = PART_OFF  + (size_t)BB * 8 * HH * 4;  // tagged h u32 [2][BB][HH]
static constexpr size_t WS_NEED   = TBUF_OFF  + (size_t)2 * BB * HH * 4;  // ~145.2 MB

__device__ __forceinline__ unsigned short f2bf(float f) {
  union { float f; uint32_t u; } v; v.f = f;
  uint32_t r = v.u + 0x7FFFu + ((v.u >> 16) & 1u);   // RNE
  return (unsigned short)(r >> 16);
}
__device__ __forceinline__ float bf2f(unsigned short s) {
  union { uint32_t u; float f; } v; v.u = ((uint32_t)s) << 16;
  return v.f;
}
__device__ __forceinline__ float sigmoidf_fast(float x) { return 1.f / (1.f + __expf(-x)); }
__device__ __forceinline__ float tanhf_fast(float x) {
  float ax = fabsf(x);
  float e  = __expf(2.f * ax);            // inf ok for large ax
  float t  = 1.f - 2.f / (e + 1.f);       // -> 1 as e -> inf
  return copysignf(t, x);
}
__device__ __forceinline__ void async_cp16(const void* g, void* lds) {
  __builtin_amdgcn_global_load_lds((const __attribute__((address_space(1))) uint32_t*)g,
                                   (__attribute__((address_space(3))) uint32_t*)lds, 16, 0, 0);
}

// ---------------- fp32 -> bf16 convert (vectorized) ----------------
__global__ __launch_bounds__(256) void k_f32_to_bf16(const float* __restrict__ s,
                                                     unsigned short* __restrict__ d, int n4) {
  int i = blockIdx.x * 256 + threadIdx.x;
  int stride = gridDim.x * 256;
  for (; i < n4; i += stride) {
    float4 v = ((const float4*)s)[i];
    ushort4 o;
    o.x = f2bf(v.x); o.y = f2bf(v.y); o.z = f2bf(v.z); o.w = f2bf(v.w);
    ((ushort4*)d)[i] = o;
  }
}

// ---------------- xg = x @ W_ih^T + (b_ih + b_hh), bf16 MFMA ----------------
__global__ __launch_bounds__(256) void k_gemm_xg(const unsigned short* __restrict__ A,
                                                 const unsigned short* __restrict__ Bw,
                                                 const float* __restrict__ b_ih,
                                                 const float* __restrict__ b_hh,
                                                 unsigned short* __restrict__ C) {
  __shared__ __align__(16) unsigned short As[128 * 32];
  __shared__ __align__(16) unsigned short Bs[128 * 32];
  const int bid = blockIdx.x;
  const int bn = bid & 15, bm = bid >> 4;
  const int row0 = bm * 128, col0 = bn * 128;
  const int tid = threadIdx.x;
  const int lane = tid & 63, w = tid >> 6;
  const int wr = w >> 1, wc = w & 1;
  const int l15 = lane & 15, l4 = lane >> 4;

  const f32x4_t z4 = {0.f, 0.f, 0.f, 0.f};
  f32x4_t acc[4][4];
#pragma unroll
  for (int mi = 0; mi < 4; ++mi)
#pragma unroll
    for (int ni = 0; ni < 4; ++ni) acc[mi][ni] = z4;

  const unsigned short* ga = A  + (size_t)(row0 + (tid >> 2)) * DD + (tid & 3) * 8;
  const unsigned short* gb = Bw + (size_t)(col0 + (tid >> 2)) * DD + (tid & 3) * 8;
  unsigned short* asw = As + w * 512;
  unsigned short* bsw = Bs + w * 512;

  for (int k0 = 0; k0 < DD; k0 += 32) {
    async_cp16(ga + k0,           asw);
    async_cp16(ga + k0 + 64 * DD, asw + 2048);
    async_cp16(gb + k0,           bsw);
    async_cp16(gb + k0 + 64 * DD, bsw + 2048);
    __syncthreads();
    bf16x8_t af[4], bfr[4];
#pragma unroll
    for (int mi = 0; mi < 4; ++mi)
      af[mi] = *(const bf16x8_t*)(As + (wr * 64 + mi * 16 + l15) * 32 + l4 * 8);
#pragma unroll
    for (int ni = 0; ni < 4; ++ni)
      bfr[ni] = *(const bf16x8_t*)(Bs + (wc * 64 + ni * 16 + l15) * 32 + l4 * 8);
#pragma unroll
    for (int mi = 0; mi < 4; ++mi)
#pragma unroll
      for (int ni = 0; ni < 4; ++ni)
        acc[mi][ni] = MFMA_BF16(af[mi], bfr[ni], acc[mi][ni]);
    __syncthreads();
  }
#pragma unroll
  for (int ni = 0; ni < 4; ++ni) {
    int col = col0 + wc * 64 + ni * 16 + l15;
    float bias = b_ih[col] + b_hh[col];
#pragma unroll
    for (int mi = 0; mi < 4; ++mi) {
      int rowb = row0 + wr * 64 + mi * 16 + l4 * 4;
#pragma unroll
      for (int r = 0; r < 4; ++r)
        C[(size_t)(rowb + r) * GG + col] = f2bf(acc[mi][ni][r] + bias);
    }
  }
}

// ---------------- LSTM recurrence ----------------
// 16 WGs per batch, fence-free tagged-data exchange (relaxed agent-scope u32
// stores carrying (tag<<16)|bf16). Per step: 2-deep pipelined poll -> LDS stage
// -> 4 independent MFMA chains of 8 -> per-wave gate activations (pre-barrier)
// -> 32-thread tail: c update, tanh, publish-first.
__global__ __launch_bounds__(256, 1) void k_lstm(const unsigned short* __restrict__ Whh,
                                                 const unsigned short* __restrict__ xg,
                                                 float* __restrict__ h_all,
                                                 unsigned int* tbuf) {
  const int bid = blockIdx.x;
  const int b  = (bid & 7) + 8 * (bid >> 7);
  const int wg = (bid >> 3) & 15;
  const int tid = threadIdx.x;
  const int lane = tid & 63, w = tid >> 6;    // wave w handles gate w (0=i,1=f,2=g,3=o)
  const int l15 = lane & 15, l4 = lane >> 4;
  const int K0 = wg * 32;

  __shared__ float gl[4][32];                 // activated gates
  __shared__ __align__(16) unsigned short h_lds[HH];

  // preload W_hh fragments: A[row][k], row=lane&15, k=(lane>>4)*8+j
  bf16x8_t wf[2][16];
#pragma unroll
  for (int mi = 0; mi < 2; ++mi) {
    const unsigned short* wrow = Whh + (size_t)(w * HH + K0 + mi * 16 + l15) * HH + l4 * 8;
#pragma unroll
    for (int kt = 0; kt < 16; ++kt)
      wf[mi][kt] = *(const bf16x8_t*)(wrow + kt * 32);
  }

  float c_reg = 0.f;
  const f32x4_t z4 = {0.f, 0.f, 0.f, 0.f};

  // per-wave xg prefetch (meaningful for lanes l15==0): gate w, rows K0+l4*4(+16)
  const unsigned short* xgw = xg + (size_t)(b << 10) * GG + w * HH + K0 + l4 * 4;
  float xfa[4], xfb[4];
  {
    ushort4 ua = *(const ushort4*)xgw;
    ushort4 ub = *(const ushort4*)(xgw + 16);
    xfa[0] = bf2f(ua.x); xfa[1] = bf2f(ua.y); xfa[2] = bf2f(ua.z); xfa[3] = bf2f(ua.w);
    xfb[0] = bf2f(ub.x); xfb[1] = bf2f(ub.y); xfb[2] = bf2f(ub.z); xfb[3] = bf2f(ub.w);
  }

  for (int t = 0; t < LL; ++t) {
    // issue next step's xg loads early (latency hides under poll + MFMA)
    const int tn = (t + 1 < LL) ? t + 1 : t;
    ushort4 ua = *(const ushort4*)(xgw + (size_t)tn * GG);
    ushort4 ub = *(const ushort4*)(xgw + (size_t)tn * GG + 16);

    // ---- poll this step's h (tag == t), 2-deep pipelined ----
    unsigned long long* src = (unsigned long long*)(tbuf + (((t & 1) * BB + b) << 9)) + tid;
    const unsigned long long tg = (unsigned long long)(unsigned int)t;
    unsigned long long v;
    {
      unsigned long long p0 = __hip_atomic_load(src, __ATOMIC_RELAXED, __HIP_MEMORY_SCOPE_AGENT);
      unsigned long long p1 = __hip_atomic_load(src, __ATOMIC_RELAXED, __HIP_MEMORY_SCOPE_AGENT);
      unsigned int guard = 0;
      for (;;) {
        if ((((p0 >> 16) & 0xFFFFull) == tg) && ((p0 >> 48) == tg)) { v = p0; break; }
        p0 = p1;
        p1 = __hip_atomic_load(src, __ATOMIC_RELAXED, __HIP_MEMORY_SCOPE_AGENT);
        if (++guard > (1u << 20)) { v = p0; break; }   // failsafe: wrong-answer beats a hang
      }
    }
    ushort2 hv2; hv2.x = (unsigned short)v; hv2.y = (unsigned short)(v >> 32);
    ((ushort2*)h_lds)[tid] = hv2;
    __syncthreads();

    // ---- gates: 4 independent MFMA chains of 8 ----
    f32x4_t a0a = z4, a0b = z4, a1a = z4, a1b = z4;
#pragma unroll
    for (int kt = 0; kt < 8; ++kt) {
      bf16x8_t hva = *(const bf16x8_t*)(h_lds + kt * 32 + l4 * 8);
      bf16x8_t hvb = *(const bf16x8_t*)(h_lds + (kt + 8) * 32 + l4 * 8);
      a0a = MFMA_BF16(wf[0][kt],     hva, a0a);
      a1a = MFMA_BF16(wf[1][kt],     hva, a1a);
      a0b = MFMA_BF16(wf[0][kt + 8], hvb, a0b);
      a1b = MFMA_BF16(wf[1][kt + 8], hvb, a1b);
    }

    // ---- per-wave activation (pre-barrier): wave 2 = tanh, others = sigmoid ----
    if (l15 == 0) {
      f32x4_t acc0 = a0a + a0b, acc1 = a1a + a1b;
#pragma unroll
      for (int r = 0; r < 4; ++r) {
        float g0 = acc0[r] + xfa[r];
        float g1 = acc1[r] + xfb[r];
        gl[w][l4 * 4 + r]      = (w == 2) ? tanhf_fast(g0) : sigmoidf_fast(g0);
        gl[w][16 + l4 * 4 + r] = (w == 2) ? tanhf_fast(g1) : sigmoidf_fast(g1);
      }
    }
    __syncthreads();

    // ---- tail (32 threads): c update, publish first, then fp32 output ----
    if (tid < 32) {
      float gi = gl[0][tid], gf = gl[1][tid], gc = gl[2][tid], go = gl[3][tid];
      c_reg = gf * c_reg + gi * gc;
      float h = go * tanhf_fast(c_reg);
      unsigned int word = ((unsigned int)(t + 1) << 16) | (unsigned int)f2bf(h);
      unsigned int* dst = tbuf + ((((t + 1) & 1) * BB + b) << 9) + K0 + tid;
      __hip_atomic_store(dst, word, __ATOMIC_RELAXED, __HIP_MEMORY_SCOPE_AGENT);
      h_all[(size_t)((b << 10) + t) * HH + K0 + tid] = h;
    }

    // convert next step's xg (loads long since complete)
    xfa[0] = bf2f(ua.x); xfa[1] = bf2f(ua.y); xfa[2] = bf2f(ua.z); xfa[3] = bf2f(ua.w);
    xfb[0] = bf2f(ub.x); xfb[1] = bf2f(ub.y); xfb[2] = bf2f(ub.z); xfb[3] = bf2f(ub.w);
  }
}

// ---------------- g = argmax(logits) as float ----------------
__global__ __launch_bounds__(256) void k_gsel(const float* __restrict__ h, const float* __restrict__ Wlin,
                                              const float* __restrict__ blin, float* __restrict__ g) {
  const int lane = threadIdx.x & 63, w = threadIdx.x >> 6;
  const int idx = blockIdx.x * 4 + w;
  const float4* hp = (const float4*)(h + (size_t)idx * HH + lane * 8);
  const float4* w0 = (const float4*)(Wlin + lane * 8);
  const float4* w1 = (const float4*)(Wlin + HH + lane * 8);
  float4 h0 = hp[0], h1 = hp[1];
  float4 a0 = w0[0], a1 = w0[1], c0 = w1[0], c1 = w1[1];
  float s0 = h0.x*a0.x + h0.y*a0.y + h0.z*a0.z + h0.w*a0.w
           + h1.x*a1.x + h1.y*a1.y + h1.z*a1.z + h1.w*a1.w;
  float s1 = h0.x*c0.x + h0.y*c0.y + h0.z*c0.z + h0.w*c0.w
           + h1.x*c1.x + h1.y*c1.y + h1.z*c1.z + h1.w*c1.w;
#pragma unroll
  for (int off = 32; off > 0; off >>= 1) {
    s0 += __shfl_xor(s0, off);
    s1 += __shfl_xor(s1, off);
  }
  if (lane == 0) g[idx] = (s1 + blin[1] > s0 + blin[0]) ? 1.f : 0.f;
}

// ---------------- scan phase A: per-(b,seg,k) partial sums of g*h ----------------
__global__ __launch_bounds__(256) void k_scan_a(const float* __restrict__ h, const float* __restrict__ g,
                                                float* __restrict__ part) {
  const int bid = blockIdx.x;
  const int b = bid >> 4, seg = (bid >> 1) & 7, kc = bid & 1;
  const int k = kc * 256 + threadIdx.x;
  __shared__ float gs[128];
  if (threadIdx.x < 128) gs[threadIdx.x] = g[b * LL + seg * 128 + threadIdx.x];
  __syncthreads();
  const float* hp = h + ((size_t)(b * LL + seg * 128)) * HH + k;
  float sum = 0.f;
#pragma unroll 4
  for (int l = 0; l < 128; ++l) sum += gs[l] * hp[(size_t)l * HH];
  part[(b * 8 + seg) * HH + k] = sum;
}

// ---------------- scan phase B: emit 2h + fa*S_excl + ba*(S_tot - S_incl) ----------------
__global__ __launch_bounds__(256) void k_scan_b(float* __restrict__ h, const float* __restrict__ g,
                                                const float* __restrict__ part,
                                                const float* __restrict__ fwd, const float* __restrict__ bwd) {
  const int bid = blockIdx.x;
  const int b = bid >> 4, seg = (bid >> 1) & 7, kc = bid & 1;
  const int k = kc * 256 + threadIdx.x;
  __shared__ float gs[128];
  if (threadIdx.x < 128) gs[threadIdx.x] = g[b * LL + seg * 128 + threadIdx.x];
  __syncthreads();
  float base = 0.f, total = 0.f;
#pragma unroll
  for (int s = 0; s < 8; ++s) {
    float v = part[(b * 8 + s) * HH + k];
    total += v;
    if (s < seg) base += v;
  }
  const float fa = fwd[k], ba = bwd[k];
  float run = base;
  float* hp = h + ((size_t)(b * LL + seg * 128)) * HH + k;
  for (int l = 0; l < 128; ++l) {
    float hv = hp[(size_t)l * HH];
    float term = gs[l] * hv;
    hp[(size_t)l * HH] = 2.f * hv + fa * run + ba * (total - run - term);
    run += term;
  }
}

extern "C" void kernel_launch(void* const* d_in, const int* in_sizes, int n_in,
                              void* d_out, int out_size, void* d_ws, size_t ws_size,
                              hipStream_t stream) {
  if (ws_size < WS_NEED) return;
  const float* x    = (const float*)d_in[0];
  const float* Wih  = (const float*)d_in[1];
  const float* Whh  = (const float*)d_in[2];
  const float* b_ih = (const float*)d_in[3];
  const float* b_hh = (const float*)d_in[4];
  const float* Wlin = (const float*)d_in[5];
  const float* blin = (const float*)d_in[6];
  const float* fwd  = (const float*)d_in[7];
  const float* bwd  = (const float*)d_in[8];
  char* ws = (char*)d_ws;
  unsigned short* xbf   = (unsigned short*)(ws + XBF_OFF);
  unsigned short* wihbf = (unsigned short*)(ws + WIHBF_OFF);
  unsigned short* whhbf = (unsigned short*)(ws + WHHBF_OFF);
  unsigned short* xgbf  = (unsigned short*)(ws + XGBF_OFF);
  float*          garr  = (float*)(ws + GARR_OFF);
  float*          part  = (float*)(ws + PART_OFF);
  unsigned int*   tbuf  = (unsigned int*)(ws + TBUF_OFF);
  float* out = (float*)d_out;

  // zero tagged h buffer: tag 0 == valid h[-1] = 0 (deterministic across graph replays)
  (void)hipMemsetAsync(ws + TBUF_OFF, 0, (size_t)2 * BB * HH * 4, stream);

  k_f32_to_bf16<<<2048, 256, 0, stream>>>(x,   xbf,   MM * DD / 4);
  k_f32_to_bf16<<<1024, 256, 0, stream>>>(Wih, wihbf, GG * DD / 4);
  k_f32_to_bf16<<<256,  256, 0, stream>>>(Whh, whhbf, GG * HH / 4);
  k_gemm_xg<<<(MM / 128) * (GG / 128), 256, 0, stream>>>(xbf, wihbf, b_ih, b_hh, xgbf);
  k_lstm<<<256, 256, 0, stream>>>(whhbf, xgbf, out, tbuf);
  k_gsel<<<MM / 4, 256, 0, stream>>>(out, Wlin, blin, garr);
  k_scan_a<<<256, 256, 0, stream>>>(out, garr, part);
  k_scan_b<<<256, 256, 0, stream>>>(out, garr, part, fwd, bwd);
}

// Round 4
// 2218.614 us; speedup vs baseline: 1.0275x; 1.0275x over previous
//
#include <hip/hip_runtime.h>
#include <stdint.h>

typedef __bf16 bf16x8_t __attribute__((ext_vector_type(8)));
typedef float  f32x4_t  __attribute__((ext_vector_type(4)));

#define MFMA_BF16(A, Bv, C) __builtin_amdgcn_mfma_f32_16x16x32_bf16((A), (Bv), (C), 0, 0, 0)

static constexpr int BB = 16;      // batch
static constexpr int LL = 1024;    // seq len
static constexpr int DD = 2048;    // input dim
static constexpr int HH = 512;     // hidden
static constexpr int GG = 4 * HH;  // 2048 gate rows
static constexpr int MM = BB * LL; // 16384

// ---- workspace layout (bytes) ----
static constexpr size_t XBF_OFF   = 0;                                    // x bf16 [MM][DD]
static constexpr size_t WIHBF_OFF = XBF_OFF   + (size_t)MM * DD * 2;      // W_ih bf16 [GG][DD]
static constexpr size_t WHHBF_OFF = WIHBF_OFF + (size_t)GG * DD * 2;      // W_hh bf16 [GG][HH]
static constexpr size_t XGBF_OFF  = WHHBF_OFF + (size_t)GG * HH * 2;      // xg bf16 [MM][GG]
static constexpr size_t GARR_OFF  = XGBF_OFF  + (size_t)MM * GG * 2;      // g f32 [MM]
static constexpr size_t PART_OFF  = GARR_OFF  + (size_t)MM * 4;           // partials f32 [BB][8][HH]
static constexpr size_t TBUF_OFF  = PART_OFF  + (size_t)BB * 8 * HH * 4;  // tagged h u32 [2][BB][HH]
static constexpr size_t WS_NEED   = TBUF_OFF  + (size_t)2 * BB * HH * 4;  // ~145.2 MB

__device__ __forceinline__ unsigned short f2bf(float f) {
  union { float f; uint32_t u; } v; v.f = f;
  uint32_t r = v.u + 0x7FFFu + ((v.u >> 16) & 1u);   // RNE
  return (unsigned short)(r >> 16);
}
__device__ __forceinline__ float bf2f(unsigned short s) {
  union { uint32_t u; float f; } v; v.u = ((uint32_t)s) << 16;
  return v.f;
}
__device__ __forceinline__ float sigmoidf_fast(float x) { return 1.f / (1.f + __expf(-x)); }
__device__ __forceinline__ float tanhf_fast(float x) {
  float ax = fabsf(x);
  float e  = __expf(2.f * ax);            // inf ok for large ax
  float t  = 1.f - 2.f / (e + 1.f);       // -> 1 as e -> inf
  return copysignf(t, x);
}
__device__ __forceinline__ void async_cp16(const void* g, void* lds) {
  __builtin_amdgcn_global_load_lds((const __attribute__((address_space(1))) uint32_t*)g,
                                   (__attribute__((address_space(3))) uint32_t*)lds, 16, 0, 0);
}

// ---------------- fp32 -> bf16 convert (vectorized) ----------------
__global__ __launch_bounds__(256) void k_f32_to_bf16(const float* __restrict__ s,
                                                     unsigned short* __restrict__ d, int n4) {
  int i = blockIdx.x * 256 + threadIdx.x;
  int stride = gridDim.x * 256;
  for (; i < n4; i += stride) {
    float4 v = ((const float4*)s)[i];
    ushort4 o;
    o.x = f2bf(v.x); o.y = f2bf(v.y); o.z = f2bf(v.z); o.w = f2bf(v.w);
    ((ushort4*)d)[i] = o;
  }
}

// ---------------- xg = x @ W_ih^T + (b_ih + b_hh), bf16 MFMA ----------------
__global__ __launch_bounds__(256) void k_gemm_xg(const unsigned short* __restrict__ A,
                                                 const unsigned short* __restrict__ Bw,
                                                 const float* __restrict__ b_ih,
                                                 const float* __restrict__ b_hh,
                                                 unsigned short* __restrict__ C) {
  __shared__ __align__(16) unsigned short As[128 * 32];
  __shared__ __align__(16) unsigned short Bs[128 * 32];
  const int bid = blockIdx.x;
  const int bn = bid & 15, bm = bid >> 4;
  const int row0 = bm * 128, col0 = bn * 128;
  const int tid = threadIdx.x;
  const int lane = tid & 63, w = tid >> 6;
  const int wr = w >> 1, wc = w & 1;
  const int l15 = lane & 15, l4 = lane >> 4;

  const f32x4_t z4 = {0.f, 0.f, 0.f, 0.f};
  f32x4_t acc[4][4];
#pragma unroll
  for (int mi = 0; mi < 4; ++mi)
#pragma unroll
    for (int ni = 0; ni < 4; ++ni) acc[mi][ni] = z4;

  const unsigned short* ga = A  + (size_t)(row0 + (tid >> 2)) * DD + (tid & 3) * 8;
  const unsigned short* gb = Bw + (size_t)(col0 + (tid >> 2)) * DD + (tid & 3) * 8;
  unsigned short* asw = As + w * 512;
  unsigned short* bsw = Bs + w * 512;

  for (int k0 = 0; k0 < DD; k0 += 32) {
    async_cp16(ga + k0,           asw);
    async_cp16(ga + k0 + 64 * DD, asw + 2048);
    async_cp16(gb + k0,           bsw);
    async_cp16(gb + k0 + 64 * DD, bsw + 2048);
    __syncthreads();
    bf16x8_t af[4], bfr[4];
#pragma unroll
    for (int mi = 0; mi < 4; ++mi)
      af[mi] = *(const bf16x8_t*)(As + (wr * 64 + mi * 16 + l15) * 32 + l4 * 8);
#pragma unroll
    for (int ni = 0; ni < 4; ++ni)
      bfr[ni] = *(const bf16x8_t*)(Bs + (wc * 64 + ni * 16 + l15) * 32 + l4 * 8);
#pragma unroll
    for (int mi = 0; mi < 4; ++mi)
#pragma unroll
      for (int ni = 0; ni < 4; ++ni)
        acc[mi][ni] = MFMA_BF16(af[mi], bfr[ni], acc[mi][ni]);
    __syncthreads();
  }
#pragma unroll
  for (int ni = 0; ni < 4; ++ni) {
    int col = col0 + wc * 64 + ni * 16 + l15;
    float bias = b_ih[col] + b_hh[col];
#pragma unroll
    for (int mi = 0; mi < 4; ++mi) {
      int rowb = row0 + wr * 64 + mi * 16 + l4 * 4;
#pragma unroll
      for (int r = 0; r < 4; ++r)
        C[(size_t)(rowb + r) * GG + col] = f2bf(acc[mi][ni][r] + bias);
    }
  }
}

// ---------------- LSTM recurrence ----------------
// 16 WGs per batch, fence-free tagged-data exchange (relaxed agent-scope u32
// stores carrying (tag<<16)|bf16). Per step:
//   clean poll (nothing in vmcnt) -> LDS stage -> barrier ->
//   xg[t+1] prefetch issue (l15==0 lanes only) -> 4 MFMA chains of 8 ->
//   per-wave activation w/ xg[t] (pre-barrier) -> barrier ->
//   tail: c=f*c+i*g, tanh, publish-first, fp32 out; then convert xg[t+1].
__global__ __launch_bounds__(256, 1) void k_lstm(const unsigned short* __restrict__ Whh,
                                                 const unsigned short* __restrict__ xg,
                                                 float* __restrict__ h_all,
                                                 unsigned int* tbuf) {
  const int bid = blockIdx.x;
  const int b  = (bid & 7) + 8 * (bid >> 7);  // same-XCD grouping heuristic
  const int wg = (bid >> 3) & 15;
  const int tid = threadIdx.x;
  const int lane = tid & 63, w = tid >> 6;    // wave w handles gate w (0=i,1=f,2=g,3=o)
  const int l15 = lane & 15, l4 = lane >> 4;
  const int K0 = wg * 32;

  __shared__ float gl[4][32];                 // activated gates
  __shared__ __align__(16) unsigned short h_lds[HH];

  // preload W_hh fragments: A[row][k], row=lane&15, k=(lane>>4)*8+j
  bf16x8_t wf[2][16];
#pragma unroll
  for (int mi = 0; mi < 2; ++mi) {
    const unsigned short* wrow = Whh + (size_t)(w * HH + K0 + mi * 16 + l15) * HH + l4 * 8;
#pragma unroll
    for (int kt = 0; kt < 16; ++kt)
      wf[mi][kt] = *(const bf16x8_t*)(wrow + kt * 32);
  }

  float c_reg = 0.f;
  const f32x4_t z4 = {0.f, 0.f, 0.f, 0.f};
  const bool act_lane = (l15 == 0);

  // per-wave xg: gate w, rows K0+l4*4 (+16); only l15==0 lanes use these.
  const unsigned short* xgw = xg + (size_t)(b << 10) * GG + w * HH + K0 + l4 * 4;
  float xfa[4], xfb[4];
  if (act_lane) {
    ushort4 ua = *(const ushort4*)xgw;
    ushort4 ub = *(const ushort4*)(xgw + 16);
    xfa[0] = bf2f(ua.x); xfa[1] = bf2f(ua.y); xfa[2] = bf2f(ua.z); xfa[3] = bf2f(ua.w);
    xfb[0] = bf2f(ub.x); xfb[1] = bf2f(ub.y); xfb[2] = bf2f(ub.z); xfb[3] = bf2f(ub.w);
  }

  for (int t = 0; t < LL; ++t) {
    // ---- clean poll: no outstanding VMEM ahead of the tag check ----
    unsigned long long* src = (unsigned long long*)(tbuf + (((t & 1) * BB + b) << 9)) + tid;
    const unsigned long long tg = (unsigned long long)(unsigned int)t;
    unsigned long long v;
    {
      unsigned long long p0 = __hip_atomic_load(src, __ATOMIC_RELAXED, __HIP_MEMORY_SCOPE_AGENT);
      unsigned long long p1 = __hip_atomic_load(src, __ATOMIC_RELAXED, __HIP_MEMORY_SCOPE_AGENT);
      unsigned int guard = 0;
      for (;;) {
        if ((((p0 >> 16) & 0xFFFFull) == tg) && ((p0 >> 48) == tg)) { v = p0; break; }
        p0 = p1;
        p1 = __hip_atomic_load(src, __ATOMIC_RELAXED, __HIP_MEMORY_SCOPE_AGENT);
        if (++guard > (1u << 20)) { v = p0; break; }   // failsafe: wrong-answer beats a hang
      }
    }
    ushort2 hv2; hv2.x = (unsigned short)v; hv2.y = (unsigned short)(v >> 32);
    ((ushort2*)h_lds)[tid] = hv2;
    __syncthreads();

    // ---- issue next step's xg loads (l15==0 lanes only; hides under MFMA) ----
    ushort4 ua, ub;
    const int tn = (t + 1 < LL) ? t + 1 : t;
    if (act_lane) {
      ua = *(const ushort4*)(xgw + (size_t)tn * GG);
      ub = *(const ushort4*)(xgw + (size_t)tn * GG + 16);
    }

    // ---- gates: 4 independent MFMA chains of 8 ----
    f32x4_t a0a = z4, a0b = z4, a1a = z4, a1b = z4;
#pragma unroll
    for (int kt = 0; kt < 8; ++kt) {
      bf16x8_t hva = *(const bf16x8_t*)(h_lds + kt * 32 + l4 * 8);
      bf16x8_t hvb = *(const bf16x8_t*)(h_lds + (kt + 8) * 32 + l4 * 8);
      a0a = MFMA_BF16(wf[0][kt],     hva, a0a);
      a1a = MFMA_BF16(wf[1][kt],     hva, a1a);
      a0b = MFMA_BF16(wf[0][kt + 8], hvb, a0b);
      a1b = MFMA_BF16(wf[1][kt + 8], hvb, a1b);
    }

    // ---- per-wave activation with xg[t] (pre-barrier): wave 2 tanh, others sigmoid ----
    if (act_lane) {
      f32x4_t acc0 = a0a + a0b, acc1 = a1a + a1b;
#pragma unroll
      for (int r = 0; r < 4; ++r) {
        float g0 = acc0[r] + xfa[r];
        float g1 = acc1[r] + xfb[r];
        gl[w][l4 * 4 + r]      = (w == 2) ? tanhf_fast(g0) : sigmoidf_fast(g0);
        gl[w][16 + l4 * 4 + r] = (w == 2) ? tanhf_fast(g1) : sigmoidf_fast(g1);
      }
    }
    __syncthreads();

    // ---- tail (32 threads): c update, publish first, then fp32 output ----
    if (tid < 32) {
      float gi = gl[0][tid], gf = gl[1][tid], gc = gl[2][tid], go = gl[3][tid];
      c_reg = gf * c_reg + gi * gc;
      float h = go * tanhf_fast(c_reg);
      unsigned int word = ((unsigned int)(t + 1) << 16) | (unsigned int)f2bf(h);
      unsigned int* dst = tbuf + ((((t + 1) & 1) * BB + b) << 9) + K0 + tid;
      __hip_atomic_store(dst, word, __ATOMIC_RELAXED, __HIP_MEMORY_SCOPE_AGENT);
      h_all[(size_t)((b << 10) + t) * HH + K0 + tid] = h;
    }

    // ---- consume xg[t+1] loads (after activation used xfa/xfb) ----
    if (act_lane) {
      xfa[0] = bf2f(ua.x); xfa[1] = bf2f(ua.y); xfa[2] = bf2f(ua.z); xfa[3] = bf2f(ua.w);
      xfb[0] = bf2f(ub.x); xfb[1] = bf2f(ub.y); xfb[2] = bf2f(ub.z); xfb[3] = bf2f(ub.w);
    }
  }
}

// ---------------- g = argmax(logits) as float ----------------
__global__ __launch_bounds__(256) void k_gsel(const float* __restrict__ h, const float* __restrict__ Wlin,
                                              const float* __restrict__ blin, float* __restrict__ g) {
  const int lane = threadIdx.x & 63, w = threadIdx.x >> 6;
  const int idx = blockIdx.x * 4 + w;
  const float4* hp = (const float4*)(h + (size_t)idx * HH + lane * 8);
  const float4* w0 = (const float4*)(Wlin + lane * 8);
  const float4* w1 = (const float4*)(Wlin + HH + lane * 8);
  float4 h0 = hp[0], h1 = hp[1];
  float4 a0 = w0[0], a1 = w0[1], c0 = w1[0], c1 = w1[1];
  float s0 = h0.x*a0.x + h0.y*a0.y + h0.z*a0.z + h0.w*a0.w
           + h1.x*a1.x + h1.y*a1.y + h1.z*a1.z + h1.w*a1.w;
  float s1 = h0.x*c0.x + h0.y*c0.y + h0.z*c0.z + h0.w*c0.w
           + h1.x*c1.x + h1.y*c1.y + h1.z*c1.z + h1.w*c1.w;
#pragma unroll
  for (int off = 32; off > 0; off >>= 1) {
    s0 += __shfl_xor(s0, off);
    s1 += __shfl_xor(s1, off);
  }
  if (lane == 0) g[idx] = (s1 + blin[1] > s0 + blin[0]) ? 1.f : 0.f;
}

// ---------------- scan phase A: per-(b,seg,k) partial sums of g*h ----------------
__global__ __launch_bounds__(256) void k_scan_a(const float* __restrict__ h, const float* __restrict__ g,
                                                float* __restrict__ part) {
  const int bid = blockIdx.x;
  const int b = bid >> 4, seg = (bid >> 1) & 7, kc = bid & 1;
  const int k = kc * 256 + threadIdx.x;
  __shared__ float gs[128];
  if (threadIdx.x < 128) gs[threadIdx.x] = g[b * LL + seg * 128 + threadIdx.x];
  __syncthreads();
  const float* hp = h + ((size_t)(b * LL + seg * 128)) * HH + k;
  float sum = 0.f;
#pragma unroll 4
  for (int l = 0; l < 128; ++l) sum += gs[l] * hp[(size_t)l * HH];
  part[(b * 8 + seg) * HH + k] = sum;
}

// ---------------- scan phase B: emit 2h + fa*S_excl + ba*(S_tot - S_incl) ----------------
__global__ __launch_bounds__(256) void k_scan_b(float* __restrict__ h, const float* __restrict__ g,
                                                const float* __restrict__ part,
                                                const float* __restrict__ fwd, const float* __restrict__ bwd) {
  const int bid = blockIdx.x;
  const int b = bid >> 4, seg = (bid >> 1) & 7, kc = bid & 1;
  const int k = kc * 256 + threadIdx.x;
  __shared__ float gs[128];
  if (threadIdx.x < 128) gs[threadIdx.x] = g[b * LL + seg * 128 + threadIdx.x];
  __syncthreads();
  float base = 0.f, total = 0.f;
#pragma unroll
  for (int s = 0; s < 8; ++s) {
    float v = part[(b * 8 + s) * HH + k];
    total += v;
    if (s < seg) base += v;
  }
  const float fa = fwd[k], ba = bwd[k];
  float run = base;
  float* hp = h + ((size_t)(b * LL + seg * 128)) * HH + k;
  for (int l = 0; l < 128; ++l) {
    float hv = hp[(size_t)l * HH];
    float term = gs[l] * hv;
    hp[(size_t)l * HH] = 2.f * hv + fa * run + ba * (total - run - term);
    run += term;
  }
}

extern "C" void kernel_launch(void* const* d_in, const int* in_sizes, int n_in,
                              void* d_out, int out_size, void* d_ws, size_t ws_size,
                              hipStream_t stream) {
  if (ws_size < WS_NEED) return;
  const float* x    = (const float*)d_in[0];
  const float* Wih  = (const float*)d_in[1];
  const float* Whh  = (const float*)d_in[2];
  const float* b_ih = (const float*)d_in[3];
  const float* b_hh = (const float*)d_in[4];
  const float* Wlin = (const float*)d_in[5];
  const float* blin = (const float*)d_in[6];
  const float* fwd  = (const float*)d_in[7];
  const float* bwd  = (const float*)d_in[8];
  char* ws = (char*)d_ws;
  unsigned short* xbf   = (unsigned short*)(ws + XBF_OFF);
  unsigned short* wihbf = (unsigned short*)(ws + WIHBF_OFF);
  unsigned short* whhbf = (unsigned short*)(ws + WHHBF_OFF);
  unsigned short* xgbf  = (unsigned short*)(ws + XGBF_OFF);
  float*          garr  = (float*)(ws + GARR_OFF);
  float*          part  = (float*)(ws + PART_OFF);
  unsigned int*   tbuf  = (unsigned int*)(ws + TBUF_OFF);
  float* out = (float*)d_out;

  // zero tagged h buffer: tag 0 == valid h[-1] = 0 (deterministic across graph replays)
  (void)hipMemsetAsync(ws + TBUF_OFF, 0, (size_t)2 * BB * HH * 4, stream);

  k_f32_to_bf16<<<2048, 256, 0, stream>>>(x,   xbf,   MM * DD / 4);
  k_f32_to_bf16<<<1024, 256, 0, stream>>>(Wih, wihbf, GG * DD / 4);
  k_f32_to_bf16<<<256,  256, 0, stream>>>(Whh, whhbf, GG * HH / 4);
  k_gemm_xg<<<(MM / 128) * (GG / 128), 256, 0, stream>>>(xbf, wihbf, b_ih, b_hh, xgbf);
  k_lstm<<<256, 256, 0, stream>>>(whhbf, xgbf, out, tbuf);
  k_gsel<<<MM / 4, 256, 0, stream>>>(out, Wlin, blin, garr);
  k_scan_a<<<256, 256, 0, stream>>>(out, garr, part);
  k_scan_b<<<256, 256, 0, stream>>>(out, garr, part, fwd, bwd);
}

// Round 5
// 1655.436 us; speedup vs baseline: 1.3770x; 1.3402x over previous
//
#include <hip/hip_runtime.h>
#include <stdint.h>

typedef __bf16 bf16x8_t __attribute__((ext_vector_type(8)));
typedef float  f32x4_t  __attribute__((ext_vector_type(4)));

#define MFMA_BF16(A, Bv, C) __builtin_amdgcn_mfma_f32_16x16x32_bf16((A), (Bv), (C), 0, 0, 0)

static constexpr int BB = 16;      // batch
static constexpr int LL = 1024;    // seq len
static constexpr int DD = 2048;    // input dim
static constexpr int HH = 512;     // hidden
static constexpr int GG = 4 * HH;  // 2048 gate rows
static constexpr int MM = BB * LL; // 16384

// ---- workspace layout (bytes) ----
static constexpr size_t XBF_OFF   = 0;                                    // x bf16 [MM][DD]
static constexpr size_t WIHBF_OFF = XBF_OFF   + (size_t)MM * DD * 2;      // W_ih bf16 [GG][DD]
static constexpr size_t WHHBF_OFF = WIHBF_OFF + (size_t)GG * DD * 2;      // W_hh bf16 [GG][HH]
static constexpr size_t XGBF_OFF  = WHHBF_OFF + (size_t)GG * HH * 2;      // xg bf16 [MM][GG]
static constexpr size_t GARR_OFF  = XGBF_OFF  + (size_t)MM * GG * 2;      // g f32 [MM]
static constexpr size_t PART_OFF  = GARR_OFF  + (size_t)MM * 4;           // partials f32 [BB][8][HH]
static constexpr size_t TBUF_OFF  = PART_OFF  + (size_t)BB * 8 * HH * 4;  // tagged h u32 [2][BB][HH]
static constexpr size_t WS_NEED   = TBUF_OFF  + (size_t)2 * BB * HH * 4;  // ~145.2 MB

__device__ __forceinline__ unsigned short f2bf(float f) {
  union { float f; uint32_t u; } v; v.f = f;
  uint32_t r = v.u + 0x7FFFu + ((v.u >> 16) & 1u);   // RNE
  return (unsigned short)(r >> 16);
}
__device__ __forceinline__ float bf2f(unsigned short s) {
  union { uint32_t u; float f; } v; v.u = ((uint32_t)s) << 16;
  return v.f;
}
__device__ __forceinline__ float sigmoidf_fast(float x) { return 1.f / (1.f + __expf(-x)); }
__device__ __forceinline__ float tanhf_fast(float x) {
  float ax = fabsf(x);
  float e  = __expf(2.f * ax);            // inf ok for large ax
  float t  = 1.f - 2.f / (e + 1.f);       // -> 1 as e -> inf
  return copysignf(t, x);
}
__device__ __forceinline__ void async_cp16(const void* g, void* lds) {
  __builtin_amdgcn_global_load_lds((const __attribute__((address_space(1))) uint32_t*)g,
                                   (__attribute__((address_space(3))) uint32_t*)lds, 16, 0, 0);
}

// ---------------- fp32 -> bf16 convert (vectorized) ----------------
__global__ __launch_bounds__(256) void k_f32_to_bf16(const float* __restrict__ s,
                                                     unsigned short* __restrict__ d, int n4) {
  int i = blockIdx.x * 256 + threadIdx.x;
  int stride = gridDim.x * 256;
  for (; i < n4; i += stride) {
    float4 v = ((const float4*)s)[i];
    ushort4 o;
    o.x = f2bf(v.x); o.y = f2bf(v.y); o.z = f2bf(v.z); o.w = f2bf(v.w);
    ((ushort4*)d)[i] = o;
  }
}

// ---------------- xg = x @ W_ih^T + (b_ih + b_hh), bf16 MFMA ----------------
__global__ __launch_bounds__(256) void k_gemm_xg(const unsigned short* __restrict__ A,
                                                 const unsigned short* __restrict__ Bw,
                                                 const float* __restrict__ b_ih,
                                                 const float* __restrict__ b_hh,
                                                 unsigned short* __restrict__ C) {
  __shared__ __align__(16) unsigned short As[128 * 32];
  __shared__ __align__(16) unsigned short Bs[128 * 32];
  const int bid = blockIdx.x;
  const int bn = bid & 15, bm = bid >> 4;
  const int row0 = bm * 128, col0 = bn * 128;
  const int tid = threadIdx.x;
  const int lane = tid & 63, w = tid >> 6;
  const int wr = w >> 1, wc = w & 1;
  const int l15 = lane & 15, l4 = lane >> 4;

  const f32x4_t z4 = {0.f, 0.f, 0.f, 0.f};
  f32x4_t acc[4][4];
#pragma unroll
  for (int mi = 0; mi < 4; ++mi)
#pragma unroll
    for (int ni = 0; ni < 4; ++ni) acc[mi][ni] = z4;

  const unsigned short* ga = A  + (size_t)(row0 + (tid >> 2)) * DD + (tid & 3) * 8;
  const unsigned short* gb = Bw + (size_t)(col0 + (tid >> 2)) * DD + (tid & 3) * 8;
  unsigned short* asw = As + w * 512;
  unsigned short* bsw = Bs + w * 512;

  for (int k0 = 0; k0 < DD; k0 += 32) {
    async_cp16(ga + k0,           asw);
    async_cp16(ga + k0 + 64 * DD, asw + 2048);
    async_cp16(gb + k0,           bsw);
    async_cp16(gb + k0 + 64 * DD, bsw + 2048);
    __syncthreads();
    bf16x8_t af[4], bfr[4];
#pragma unroll
    for (int mi = 0; mi < 4; ++mi)
      af[mi] = *(const bf16x8_t*)(As + (wr * 64 + mi * 16 + l15) * 32 + l4 * 8);
#pragma unroll
    for (int ni = 0; ni < 4; ++ni)
      bfr[ni] = *(const bf16x8_t*)(Bs + (wc * 64 + ni * 16 + l15) * 32 + l4 * 8);
#pragma unroll
    for (int mi = 0; mi < 4; ++mi)
#pragma unroll
      for (int ni = 0; ni < 4; ++ni)
        acc[mi][ni] = MFMA_BF16(af[mi], bfr[ni], acc[mi][ni]);
    __syncthreads();
  }
#pragma unroll
  for (int ni = 0; ni < 4; ++ni) {
    int col = col0 + wc * 64 + ni * 16 + l15;
    float bias = b_ih[col] + b_hh[col];
#pragma unroll
    for (int mi = 0; mi < 4; ++mi) {
      int rowb = row0 + wr * 64 + mi * 16 + l4 * 4;
#pragma unroll
      for (int r = 0; r < 4; ++r)
        C[(size_t)(rowb + r) * GG + col] = f2bf(acc[mi][ni][r] + bias);
    }
  }
}

// ---------------- LSTM recurrence ----------------
// 16 WGs per batch, fence-free tagged-data exchange (relaxed agent-scope u32
// stores carrying (tag<<16)|bf16). Per step:
//   simple fresh poll (nothing in vmcnt) -> LDS stage -> barrier ->
//   per-lane scalar xg[t+1] issue (l15<8 lanes) -> 4 MFMA chains of 8 ->
//   DISTRIBUTED activation: 1 transcendental per lane (32 lanes/wave, using
//   the 16 identical D columns) -> barrier -> tail: c update, tanh, publish.
__global__ __launch_bounds__(256) void k_lstm(const unsigned short* __restrict__ Whh,
                                              const unsigned short* __restrict__ xg,
                                              float* __restrict__ h_all,
                                              unsigned int* tbuf) {
  const int bid = blockIdx.x;
  const int b  = (bid & 7) + 8 * (bid >> 7);  // same-XCD grouping heuristic
  const int wg = (bid >> 3) & 15;
  const int tid = threadIdx.x;
  const int lane = tid & 63, w = tid >> 6;    // wave w handles gate w (0=i,1=f,2=g,3=o)
  const int l15 = lane & 15, l4 = lane >> 4;
  const int K0 = wg * 32;

  __shared__ float gl[4][32];                 // activated gates
  __shared__ __align__(16) unsigned short h_lds[HH];

  // preload W_hh fragments: A[row][k], row=lane&15, k=(lane>>4)*8+j
  bf16x8_t wf[2][16];
#pragma unroll
  for (int mi = 0; mi < 2; ++mi) {
    const unsigned short* wrow = Whh + (size_t)(w * HH + K0 + mi * 16 + l15) * HH + l4 * 8;
#pragma unroll
    for (int kt = 0; kt < 16; ++kt)
      wf[mi][kt] = *(const bf16x8_t*)(wrow + kt * 32);
  }

  float c_reg = 0.f;
  const f32x4_t z4 = {0.f, 0.f, 0.f, 0.f};

  // distributed-activation lane mapping: lanes l15<8 each own one element
  // j = 16*(l15>=4) + 4*l4 + (l15&3); value source acc{0,1}[l15&3] (any column).
  const bool act_lane = (l15 < 8);
  const int r_sel = l15 & 3;
  const int jj = ((l15 >> 2) << 4) + (l4 << 2) + r_sel;
  const unsigned short* xgp = xg + (size_t)(b << 10) * GG + w * HH + K0 + jj;
  float xcur = 0.f;
  if (act_lane) xcur = bf2f(xgp[0]);          // xg[t=0]

  for (int t = 0; t < LL; ++t) {
    // ---- simple fresh poll: detect on first load after visibility ----
    unsigned long long* src = (unsigned long long*)(tbuf + (((t & 1) * BB + b) << 9)) + tid;
    const unsigned long long tg = (unsigned long long)(unsigned int)t;
    unsigned long long v;
    unsigned int guard = 0;
    for (;;) {
      v = __hip_atomic_load(src, __ATOMIC_RELAXED, __HIP_MEMORY_SCOPE_AGENT);
      if ((((v >> 16) & 0xFFFFull) == tg) && ((v >> 48) == tg)) break;
      if (++guard > (1u << 20)) break;   // failsafe: wrong-answer beats a hang
    }
    ushort2 hv2; hv2.x = (unsigned short)v; hv2.y = (unsigned short)(v >> 32);
    ((ushort2*)h_lds)[tid] = hv2;
    __syncthreads();

    // ---- issue next step's xg scalar load (act lanes; hides under MFMA) ----
    unsigned short xnx = 0;
    if (act_lane && (t + 1 < LL)) xnx = xgp[(size_t)(t + 1) * GG];

    // ---- gates: 4 independent MFMA chains of 8 ----
    f32x4_t a0a = z4, a0b = z4, a1a = z4, a1b = z4;
#pragma unroll
    for (int kt = 0; kt < 8; ++kt) {
      bf16x8_t hva = *(const bf16x8_t*)(h_lds + kt * 32 + l4 * 8);
      bf16x8_t hvb = *(const bf16x8_t*)(h_lds + (kt + 8) * 32 + l4 * 8);
      a0a = MFMA_BF16(wf[0][kt],     hva, a0a);
      a1a = MFMA_BF16(wf[1][kt],     hva, a1a);
      a0b = MFMA_BF16(wf[0][kt + 8], hvb, a0b);
      a1b = MFMA_BF16(wf[1][kt + 8], hvb, a1b);
    }

    // ---- distributed activation: one transcendental per lane ----
    if (act_lane) {
      f32x4_t s = (l15 >= 4) ? (a1a + a1b) : (a0a + a0b);
      float e01 = (r_sel & 1) ? s[1] : s[0];
      float e23 = (r_sel & 1) ? s[3] : s[2];
      float raw = ((r_sel & 2) ? e23 : e01) + xcur;
      gl[w][jj] = (w == 2) ? tanhf_fast(raw) : sigmoidf_fast(raw);
    }
    __syncthreads();

    // ---- tail (32 threads): c update, publish first, then fp32 output ----
    if (tid < 32) {
      float gi = gl[0][tid], gf = gl[1][tid], gc = gl[2][tid], go = gl[3][tid];
      c_reg = gf * c_reg + gi * gc;
      float h = go * tanhf_fast(c_reg);
      unsigned int word = ((unsigned int)(t + 1) << 16) | (unsigned int)f2bf(h);
      unsigned int* dst = tbuf + ((((t + 1) & 1) * BB + b) << 9) + K0 + tid;
      __hip_atomic_store(dst, word, __ATOMIC_RELAXED, __HIP_MEMORY_SCOPE_AGENT);
      h_all[(size_t)((b << 10) + t) * HH + K0 + tid] = h;
    }

    // ---- consume xg[t+1] (after activation used xcur) ----
    if (act_lane) xcur = bf2f(xnx);
  }
}

// ---------------- g = argmax(logits) as float ----------------
__global__ __launch_bounds__(256) void k_gsel(const float* __restrict__ h, const float* __restrict__ Wlin,
                                              const float* __restrict__ blin, float* __restrict__ g) {
  const int lane = threadIdx.x & 63, w = threadIdx.x >> 6;
  const int idx = blockIdx.x * 4 + w;
  const float4* hp = (const float4*)(h + (size_t)idx * HH + lane * 8);
  const float4* w0 = (const float4*)(Wlin + lane * 8);
  const float4* w1 = (const float4*)(Wlin + HH + lane * 8);
  float4 h0 = hp[0], h1 = hp[1];
  float4 a0 = w0[0], a1 = w0[1], c0 = w1[0], c1 = w1[1];
  float s0 = h0.x*a0.x + h0.y*a0.y + h0.z*a0.z + h0.w*a0.w
           + h1.x*a1.x + h1.y*a1.y + h1.z*a1.z + h1.w*a1.w;
  float s1 = h0.x*c0.x + h0.y*c0.y + h0.z*c0.z + h0.w*c0.w
           + h1.x*c1.x + h1.y*c1.y + h1.z*c1.z + h1.w*c1.w;
#pragma unroll
  for (int off = 32; off > 0; off >>= 1) {
    s0 += __shfl_xor(s0, off);
    s1 += __shfl_xor(s1, off);
  }
  if (lane == 0) g[idx] = (s1 + blin[1] > s0 + blin[0]) ? 1.f : 0.f;
}

// ---------------- scan phase A: per-(b,seg,k) partial sums of g*h ----------------
__global__ __launch_bounds__(256) void k_scan_a(const float* __restrict__ h, const float* __restrict__ g,
                                                float* __restrict__ part) {
  const int bid = blockIdx.x;
  const int b = bid >> 4, seg = (bid >> 1) & 7, kc = bid & 1;
  const int k = kc * 256 + threadIdx.x;
  __shared__ float gs[128];
  if (threadIdx.x < 128) gs[threadIdx.x] = g[b * LL + seg * 128 + threadIdx.x];
  __syncthreads();
  const float* hp = h + ((size_t)(b * LL + seg * 128)) * HH + k;
  float sum = 0.f;
#pragma unroll 4
  for (int l = 0; l < 128; ++l) sum += gs[l] * hp[(size_t)l * HH];
  part[(b * 8 + seg) * HH + k] = sum;
}

// ---------------- scan phase B: emit 2h + fa*S_excl + ba*(S_tot - S_incl) ----------------
__global__ __launch_bounds__(256) void k_scan_b(float* __restrict__ h, const float* __restrict__ g,
                                                const float* __restrict__ part,
                                                const float* __restrict__ fwd, const float* __restrict__ bwd) {
  const int bid = blockIdx.x;
  const int b = bid >> 4, seg = (bid >> 1) & 7, kc = bid & 1;
  const int k = kc * 256 + threadIdx.x;
  __shared__ float gs[128];
  if (threadIdx.x < 128) gs[threadIdx.x] = g[b * LL + seg * 128 + threadIdx.x];
  __syncthreads();
  float base = 0.f, total = 0.f;
#pragma unroll
  for (int s = 0; s < 8; ++s) {
    float v = part[(b * 8 + s) * HH + k];
    total += v;
    if (s < seg) base += v;
  }
  const float fa = fwd[k], ba = bwd[k];
  float run = base;
  float* hp = h + ((size_t)(b * LL + seg * 128)) * HH + k;
  for (int l = 0; l < 128; ++l) {
    float hv = hp[(size_t)l * HH];
    float term = gs[l] * hv;
    hp[(size_t)l * HH] = 2.f * hv + fa * run + ba * (total - run - term);
    run += term;
  }
}

extern "C" void kernel_launch(void* const* d_in, const int* in_sizes, int n_in,
                              void* d_out, int out_size, void* d_ws, size_t ws_size,
                              hipStream_t stream) {
  if (ws_size < WS_NEED) return;
  const float* x    = (const float*)d_in[0];
  const float* Wih  = (const float*)d_in[1];
  const float* Whh  = (const float*)d_in[2];
  const float* b_ih = (const float*)d_in[3];
  const float* b_hh = (const float*)d_in[4];
  const float* Wlin = (const float*)d_in[5];
  const float* blin = (const float*)d_in[6];
  const float* fwd  = (const float*)d_in[7];
  const float* bwd  = (const float*)d_in[8];
  char* ws = (char*)d_ws;
  unsigned short* xbf   = (unsigned short*)(ws + XBF_OFF);
  unsigned short* wihbf = (unsigned short*)(ws + WIHBF_OFF);
  unsigned short* whhbf = (unsigned short*)(ws + WHHBF_OFF);
  unsigned short* xgbf  = (unsigned short*)(ws + XGBF_OFF);
  float*          garr  = (float*)(ws + GARR_OFF);
  float*          part  = (float*)(ws + PART_OFF);
  unsigned int*   tbuf  = (unsigned int*)(ws + TBUF_OFF);
  float* out = (float*)d_out;

  // zero tagged h buffer: tag 0 == valid h[-1] = 0 (deterministic across graph replays)
  (void)hipMemsetAsync(ws + TBUF_OFF, 0, (size_t)2 * BB * HH * 4, stream);

  k_f32_to_bf16<<<2048, 256, 0, stream>>>(x,   xbf,   MM * DD / 4);
  k_f32_to_bf16<<<1024, 256, 0, stream>>>(Wih, wihbf, GG * DD / 4);
  k_f32_to_bf16<<<256,  256, 0, stream>>>(Whh, whhbf, GG * HH / 4);
  k_gemm_xg<<<(MM / 128) * (GG / 128), 256, 0, stream>>>(xbf, wihbf, b_ih, b_hh, xgbf);
  k_lstm<<<256, 256, 0, stream>>>(whhbf, xgbf, out, tbuf);
  k_gsel<<<MM / 4, 256, 0, stream>>>(out, Wlin, blin, garr);
  k_scan_a<<<256, 256, 0, stream>>>(out, garr, part);
  k_scan_b<<<256, 256, 0, stream>>>(out, garr, part, fwd, bwd);
}

// Round 6
// 1653.125 us; speedup vs baseline: 1.3790x; 1.0014x over previous
//
#include <hip/hip_runtime.h>
#include <stdint.h>

typedef __bf16 bf16x8_t __attribute__((ext_vector_type(8)));
typedef float  f32x4_t  __attribute__((ext_vector_type(4)));

#define MFMA_BF16(A, Bv, C) __builtin_amdgcn_mfma_f32_16x16x32_bf16((A), (Bv), (C), 0, 0, 0)

static constexpr int BB = 16;      // batch
static constexpr int LL = 1024;    // seq len
static constexpr int DD = 2048;    // input dim
static constexpr int HH = 512;     // hidden
static constexpr int GG = 4 * HH;  // 2048 gate rows
static constexpr int MM = BB * LL; // 16384

// ---- workspace layout (bytes) ----
static constexpr size_t XBF_OFF   = 0;                                    // x bf16 [MM][DD]
static constexpr size_t WIHBF_OFF = XBF_OFF   + (size_t)MM * DD * 2;      // W_ih bf16 [GG][DD]
static constexpr size_t WHHBF_OFF = WIHBF_OFF + (size_t)GG * DD * 2;      // W_hh bf16 [GG][HH]
static constexpr size_t XGBF_OFF  = WHHBF_OFF + (size_t)GG * HH * 2;      // xg bf16 [MM][GG]
static constexpr size_t GARR_OFF  = XGBF_OFF  + (size_t)MM * GG * 2;      // g f32 [MM]
static constexpr size_t PART_OFF  = GARR_OFF  + (size_t)MM * 4;           // partials f32 [BB][8][HH]
static constexpr size_t TBUF_OFF  = PART_OFF  + (size_t)BB * 8 * HH * 4;  // tagged h u32 [2][BB][HH]
static constexpr size_t WS_NEED   = TBUF_OFF  + (size_t)2 * BB * HH * 4;  // ~145.2 MB

__device__ __forceinline__ unsigned short f2bf(float f) {
  union { float f; uint32_t u; } v; v.f = f;
  uint32_t r = v.u + 0x7FFFu + ((v.u >> 16) & 1u);   // RNE
  return (unsigned short)(r >> 16);
}
__device__ __forceinline__ float bf2f(unsigned short s) {
  union { uint32_t u; float f; } v; v.u = ((uint32_t)s) << 16;
  return v.f;
}
__device__ __forceinline__ float sigmoidf_fast(float x) { return 1.f / (1.f + __expf(-x)); }
__device__ __forceinline__ float tanhf_fast(float x) {
  float ax = fabsf(x);
  float e  = __expf(2.f * ax);            // inf ok for large ax
  float t  = 1.f - 2.f / (e + 1.f);       // -> 1 as e -> inf
  return copysignf(t, x);
}
__device__ __forceinline__ void async_cp16(const void* g, void* lds) {
  __builtin_amdgcn_global_load_lds((const __attribute__((address_space(1))) uint32_t*)g,
                                   (__attribute__((address_space(3))) uint32_t*)lds, 16, 0, 0);
}

// ---------------- fp32 -> bf16 convert (vectorized) ----------------
__global__ __launch_bounds__(256) void k_f32_to_bf16(const float* __restrict__ s,
                                                     unsigned short* __restrict__ d, int n4) {
  int i = blockIdx.x * 256 + threadIdx.x;
  int stride = gridDim.x * 256;
  for (; i < n4; i += stride) {
    float4 v = ((const float4*)s)[i];
    ushort4 o;
    o.x = f2bf(v.x); o.y = f2bf(v.y); o.z = f2bf(v.z); o.w = f2bf(v.w);
    ((ushort4*)d)[i] = o;
  }
}

// ---------------- xg = x @ W_ih^T + (b_ih + b_hh), bf16 MFMA ----------------
__global__ __launch_bounds__(256) void k_gemm_xg(const unsigned short* __restrict__ A,
                                                 const unsigned short* __restrict__ Bw,
                                                 const float* __restrict__ b_ih,
                                                 const float* __restrict__ b_hh,
                                                 unsigned short* __restrict__ C) {
  __shared__ __align__(16) unsigned short As[128 * 32];
  __shared__ __align__(16) unsigned short Bs[128 * 32];
  const int bid = blockIdx.x;
  const int bn = bid & 15, bm = bid >> 4;
  const int row0 = bm * 128, col0 = bn * 128;
  const int tid = threadIdx.x;
  const int lane = tid & 63, w = tid >> 6;
  const int wr = w >> 1, wc = w & 1;
  const int l15 = lane & 15, l4 = lane >> 4;

  const f32x4_t z4 = {0.f, 0.f, 0.f, 0.f};
  f32x4_t acc[4][4];
#pragma unroll
  for (int mi = 0; mi < 4; ++mi)
#pragma unroll
    for (int ni = 0; ni < 4; ++ni) acc[mi][ni] = z4;

  const unsigned short* ga = A  + (size_t)(row0 + (tid >> 2)) * DD + (tid & 3) * 8;
  const unsigned short* gb = Bw + (size_t)(col0 + (tid >> 2)) * DD + (tid & 3) * 8;
  unsigned short* asw = As + w * 512;
  unsigned short* bsw = Bs + w * 512;

  for (int k0 = 0; k0 < DD; k0 += 32) {
    async_cp16(ga + k0,           asw);
    async_cp16(ga + k0 + 64 * DD, asw + 2048);
    async_cp16(gb + k0,           bsw);
    async_cp16(gb + k0 + 64 * DD, bsw + 2048);
    __syncthreads();
    bf16x8_t af[4], bfr[4];
#pragma unroll
    for (int mi = 0; mi < 4; ++mi)
      af[mi] = *(const bf16x8_t*)(As + (wr * 64 + mi * 16 + l15) * 32 + l4 * 8);
#pragma unroll
    for (int ni = 0; ni < 4; ++ni)
      bfr[ni] = *(const bf16x8_t*)(Bs + (wc * 64 + ni * 16 + l15) * 32 + l4 * 8);
#pragma unroll
    for (int mi = 0; mi < 4; ++mi)
#pragma unroll
      for (int ni = 0; ni < 4; ++ni)
        acc[mi][ni] = MFMA_BF16(af[mi], bfr[ni], acc[mi][ni]);
    __syncthreads();
  }
#pragma unroll
  for (int ni = 0; ni < 4; ++ni) {
    int col = col0 + wc * 64 + ni * 16 + l15;
    float bias = b_ih[col] + b_hh[col];
#pragma unroll
    for (int mi = 0; mi < 4; ++mi) {
      int rowb = row0 + wr * 64 + mi * 16 + l4 * 4;
#pragma unroll
      for (int r = 0; r < 4; ++r)
        C[(size_t)(rowb + r) * GG + col] = f2bf(acc[mi][ni][r] + bias);
    }
  }
}

// ---------------- LSTM recurrence ----------------
// 16 WGs per batch, fence-free tagged-data exchange (relaxed agent-scope u32
// stores carrying (tag<<16)|bf16). Weights are PINNED in VGPRs via an asm
// define-barrier: without it the compiler rematerializes the 128 weight-VGPR
// loads inside the step loop (VGPR_Count was 92 < 128), re-streaming 4 MB/XCD
// per step from L2 (~23 TB/s, ~70% of L2 ceiling) -- the R2-R5 bottleneck.
__global__ __launch_bounds__(256, 1) void k_lstm(const unsigned short* __restrict__ Whh,
                                                 const unsigned short* __restrict__ xg,
                                                 float* __restrict__ h_all,
                                                 unsigned int* tbuf) {
  const int bid = blockIdx.x;
  const int b  = (bid & 7) + 8 * (bid >> 7);  // same-XCD grouping heuristic
  const int wg = (bid >> 3) & 15;
  const int tid = threadIdx.x;
  const int lane = tid & 63, w = tid >> 6;    // wave w handles gate w (0=i,1=f,2=g,3=o)
  const int l15 = lane & 15, l4 = lane >> 4;
  const int K0 = wg * 32;

  __shared__ float gl[4][32];                 // activated gates
  __shared__ __align__(16) unsigned short h_lds[HH];

  // preload W_hh fragments: A[row][k], row=lane&15, k=(lane>>4)*8+j
  f32x4_t wfr[2][16];
#pragma unroll
  for (int mi = 0; mi < 2; ++mi) {
    const unsigned short* wrow = Whh + (size_t)(w * HH + K0 + mi * 16 + l15) * HH + l4 * 8;
#pragma unroll
    for (int kt = 0; kt < 16; ++kt)
      wfr[mi][kt] = *(const f32x4_t*)(wrow + kt * 32);
  }
  // pin: value becomes an asm output -> compiler cannot rematerialize the load
#pragma unroll
  for (int mi = 0; mi < 2; ++mi)
#pragma unroll
    for (int kt = 0; kt < 16; ++kt)
      asm volatile("" : "+v"(wfr[mi][kt]));

  float c_reg = 0.f;
  const f32x4_t z4 = {0.f, 0.f, 0.f, 0.f};

  // distributed-activation lane mapping: lanes l15<8 each own one element
  // j = 16*(l15>=4) + 4*l4 + (l15&3); value source acc{0,1}[l15&3] (any column).
  const bool act_lane = (l15 < 8);
  const int r_sel = l15 & 3;
  const int jj = ((l15 >> 2) << 4) + (l4 << 2) + r_sel;
  const unsigned short* xgp = xg + (size_t)(b << 10) * GG + w * HH + K0 + jj;
  float xcur = 0.f;
  if (act_lane) xcur = bf2f(xgp[0]);          // xg[t=0]

  for (int t = 0; t < LL; ++t) {
    // ---- simple fresh poll: detect on first load after visibility ----
    unsigned long long* src = (unsigned long long*)(tbuf + (((t & 1) * BB + b) << 9)) + tid;
    const unsigned long long tg = (unsigned long long)(unsigned int)t;
    unsigned long long v;
    unsigned int guard = 0;
    for (;;) {
      v = __hip_atomic_load(src, __ATOMIC_RELAXED, __HIP_MEMORY_SCOPE_AGENT);
      if ((((v >> 16) & 0xFFFFull) == tg) && ((v >> 48) == tg)) break;
      if (++guard > (1u << 20)) break;   // failsafe: wrong-answer beats a hang
    }
    ushort2 hv2; hv2.x = (unsigned short)v; hv2.y = (unsigned short)(v >> 32);
    ((ushort2*)h_lds)[tid] = hv2;
    __syncthreads();

    // ---- issue next step's xg scalar load (act lanes; hides under MFMA) ----
    unsigned short xnx = 0;
    if (act_lane && (t + 1 < LL)) xnx = xgp[(size_t)(t + 1) * GG];

    // ---- gates: 4 independent MFMA chains of 8, weights from pinned VGPRs ----
    f32x4_t a0a = z4, a0b = z4, a1a = z4, a1b = z4;
#pragma unroll
    for (int kt = 0; kt < 8; ++kt) {
      bf16x8_t hva = *(const bf16x8_t*)(h_lds + kt * 32 + l4 * 8);
      bf16x8_t hvb = *(const bf16x8_t*)(h_lds + (kt + 8) * 32 + l4 * 8);
      a0a = MFMA_BF16(__builtin_bit_cast(bf16x8_t, wfr[0][kt]),     hva, a0a);
      a1a = MFMA_BF16(__builtin_bit_cast(bf16x8_t, wfr[1][kt]),     hva, a1a);
      a0b = MFMA_BF16(__builtin_bit_cast(bf16x8_t, wfr[0][kt + 8]), hvb, a0b);
      a1b = MFMA_BF16(__builtin_bit_cast(bf16x8_t, wfr[1][kt + 8]), hvb, a1b);
    }

    // ---- distributed activation: one transcendental per lane ----
    if (act_lane) {
      f32x4_t s = (l15 >= 4) ? (a1a + a1b) : (a0a + a0b);
      float e01 = (r_sel & 1) ? s[1] : s[0];
      float e23 = (r_sel & 1) ? s[3] : s[2];
      float raw = ((r_sel & 2) ? e23 : e01) + xcur;
      gl[w][jj] = (w == 2) ? tanhf_fast(raw) : sigmoidf_fast(raw);
    }
    __syncthreads();

    // ---- tail (32 threads): c update, publish first, then fp32 output ----
    if (tid < 32) {
      float gi = gl[0][tid], gf = gl[1][tid], gc = gl[2][tid], go = gl[3][tid];
      c_reg = gf * c_reg + gi * gc;
      float h = go * tanhf_fast(c_reg);
      unsigned int word = ((unsigned int)(t + 1) << 16) | (unsigned int)f2bf(h);
      unsigned int* dst = tbuf + ((((t + 1) & 1) * BB + b) << 9) + K0 + tid;
      __hip_atomic_store(dst, word, __ATOMIC_RELAXED, __HIP_MEMORY_SCOPE_AGENT);
      h_all[(size_t)((b << 10) + t) * HH + K0 + tid] = h;
    }

    // ---- consume xg[t+1] (after activation used xcur) ----
    if (act_lane) xcur = bf2f(xnx);
  }
}

// ---------------- g = argmax(logits) as float ----------------
__global__ __launch_bounds__(256) void k_gsel(const float* __restrict__ h, const float* __restrict__ Wlin,
                                              const float* __restrict__ blin, float* __restrict__ g) {
  const int lane = threadIdx.x & 63, w = threadIdx.x >> 6;
  const int idx = blockIdx.x * 4 + w;
  const float4* hp = (const float4*)(h + (size_t)idx * HH + lane * 8);
  const float4* w0 = (const float4*)(Wlin + lane * 8);
  const float4* w1 = (const float4*)(Wlin + HH + lane * 8);
  float4 h0 = hp[0], h1 = hp[1];
  float4 a0 = w0[0], a1 = w0[1], c0 = w1[0], c1 = w1[1];
  float s0 = h0.x*a0.x + h0.y*a0.y + h0.z*a0.z + h0.w*a0.w
           + h1.x*a1.x + h1.y*a1.y + h1.z*a1.z + h1.w*a1.w;
  float s1 = h0.x*c0.x + h0.y*c0.y + h0.z*c0.z + h0.w*c0.w
           + h1.x*c1.x + h1.y*c1.y + h1.z*c1.z + h1.w*c1.w;
#pragma unroll
  for (int off = 32; off > 0; off >>= 1) {
    s0 += __shfl_xor(s0, off);
    s1 += __shfl_xor(s1, off);
  }
  if (lane == 0) g[idx] = (s1 + blin[1] > s0 + blin[0]) ? 1.f : 0.f;
}

// ---------------- scan phase A: per-(b,seg,k) partial sums of g*h ----------------
__global__ __launch_bounds__(256) void k_scan_a(const float* __restrict__ h, const float* __restrict__ g,
                                                float* __restrict__ part) {
  const int bid = blockIdx.x;
  const int b = bid >> 4, seg = (bid >> 1) & 7, kc = bid & 1;
  const int k = kc * 256 + threadIdx.x;
  __shared__ float gs[128];
  if (threadIdx.x < 128) gs[threadIdx.x] = g[b * LL + seg * 128 + threadIdx.x];
  __syncthreads();
  const float* hp = h + ((size_t)(b * LL + seg * 128)) * HH + k;
  float sum = 0.f;
#pragma unroll 4
  for (int l = 0; l < 128; ++l) sum += gs[l] * hp[(size_t)l * HH];
  part[(b * 8 + seg) * HH + k] = sum;
}

// ---------------- scan phase B: emit 2h + fa*S_excl + ba*(S_tot - S_incl) ----------------
__global__ __launch_bounds__(256) void k_scan_b(float* __restrict__ h, const float* __restrict__ g,
                                                const float* __restrict__ part,
                                                const float* __restrict__ fwd, const float* __restrict__ bwd) {
  const int bid = blockIdx.x;
  const int b = bid >> 4, seg = (bid >> 1) & 7, kc = bid & 1;
  const int k = kc * 256 + threadIdx.x;
  __shared__ float gs[128];
  if (threadIdx.x < 128) gs[threadIdx.x] = g[b * LL + seg * 128 + threadIdx.x];
  __syncthreads();
  float base = 0.f, total = 0.f;
#pragma unroll
  for (int s = 0; s < 8; ++s) {
    float v = part[(b * 8 + s) * HH + k];
    total += v;
    if (s < seg) base += v;
  }
  const float fa = fwd[k], ba = bwd[k];
  float run = base;
  float* hp = h + ((size_t)(b * LL + seg * 128)) * HH + k;
  for (int l = 0; l < 128; ++l) {
    float hv = hp[(size_t)l * HH];
    float term = gs[l] * hv;
    hp[(size_t)l * HH] = 2.f * hv + fa * run + ba * (total - run - term);
    run += term;
  }
}

extern "C" void kernel_launch(void* const* d_in, const int* in_sizes, int n_in,
                              void* d_out, int out_size, void* d_ws, size_t ws_size,
                              hipStream_t stream) {
  if (ws_size < WS_NEED) return;
  const float* x    = (const float*)d_in[0];
  const float* Wih  = (const float*)d_in[1];
  const float* Whh  = (const float*)d_in[2];
  const float* b_ih = (const float*)d_in[3];
  const float* b_hh = (const float*)d_in[4];
  const float* Wlin = (const float*)d_in[5];
  const float* blin = (const float*)d_in[6];
  const float* fwd  = (const float*)d_in[7];
  const float* bwd  = (const float*)d_in[8];
  char* ws = (char*)d_ws;
  unsigned short* xbf   = (unsigned short*)(ws + XBF_OFF);
  unsigned short* wihbf = (unsigned short*)(ws + WIHBF_OFF);
  unsigned short* whhbf = (unsigned short*)(ws + WHHBF_OFF);
  unsigned short* xgbf  = (unsigned short*)(ws + XGBF_OFF);
  float*          garr  = (float*)(ws + GARR_OFF);
  float*          part  = (float*)(ws + PART_OFF);
  unsigned int*   tbuf  = (unsigned int*)(ws + TBUF_OFF);
  float* out = (float*)d_out;

  // zero tagged h buffer: tag 0 == valid h[-1] = 0 (deterministic across graph replays)
  (void)hipMemsetAsync(ws + TBUF_OFF, 0, (size_t)2 * BB * HH * 4, stream);

  k_f32_to_bf16<<<2048, 256, 0, stream>>>(x,   xbf,   MM * DD / 4);
  k_f32_to_bf16<<<1024, 256, 0, stream>>>(Wih, wihbf, GG * DD / 4);
  k_f32_to_bf16<<<256,  256, 0, stream>>>(Whh, whhbf, GG * HH / 4);
  k_gemm_xg<<<(MM / 128) * (GG / 128), 256, 0, stream>>>(xbf, wihbf, b_ih, b_hh, xgbf);
  k_lstm<<<256, 256, 0, stream>>>(whhbf, xgbf, out, tbuf);
  k_gsel<<<MM / 4, 256, 0, stream>>>(out, Wlin, blin, garr);
  k_scan_a<<<256, 256, 0, stream>>>(out, garr, part);
  k_scan_b<<<256, 256, 0, stream>>>(out, garr, part, fwd, bwd);
}